// Round 1
// baseline (579.956 us; speedup 1.0000x reference)
//
#include <hip/hip_runtime.h>

#define NNODES 50000
#define NEDGES 800000
#define NTILES ((NNODES + 255) / 256)   // 196
#define XFEAT (NNODES * 384)            // 19,200,000 (divisible by 2048)
#define XPREP_BLOCKS (XFEAT / (256 * 8))  // 9375
#define WPREP_TOTAL 344064
#define WPREP_BLOCKS (WPREP_TOTAL / 256)  // 1344

typedef unsigned short ushort_t;
typedef __attribute__((ext_vector_type(8))) short short8;
typedef __attribute__((ext_vector_type(4))) float floatx4;

__device__ __forceinline__ float bf2f(unsigned short u) {
  union { unsigned int i; float f; } v; v.i = ((unsigned int)u) << 16; return v.f;
}
__device__ __forceinline__ unsigned short f2bf(float f) {
  union { float f; unsigned int i; } v; v.f = f;
  unsigned int r = v.i + 0x7fffu + ((v.i >> 16) & 1u);
  return (unsigned short)(r >> 16);
}

__device__ __forceinline__ void gload_lds16(const void* g, void* l) {
  __builtin_amdgcn_global_load_lds(
      (const __attribute__((address_space(1))) unsigned int*)g,
      (__attribute__((address_space(3))) unsigned int*)l, 16, 0, 0);
}

// ---------------- graph preprocessing ----------------

__global__ void hist_kernel(const int* dst, int* cnt) {
  int i = blockIdx.x * 256 + threadIdx.x;
  if (i < NEDGES) atomicAdd(&cnt[dst[i]], 1);
}

// ---- device-wide exclusive scan of cnt[0..NNODES) in 3 tiny kernels ----

__global__ __launch_bounds__(256) void tile_scan_kernel(
    const int* __restrict__ cnt, int* __restrict__ tile_pref, int* __restrict__ tile_sum) {
  __shared__ int s[256];
  int b = blockIdx.x, t = threadIdx.x;
  int i = b * 256 + t;
  int v = (i < NNODES) ? cnt[i] : 0;
  s[t] = v;
  __syncthreads();
#pragma unroll
  for (int off = 1; off < 256; off <<= 1) {
    int x = (t >= off) ? s[t - off] : 0;
    __syncthreads();
    s[t] += x;
    __syncthreads();
  }
  if (i < NNODES) tile_pref[i] = s[t] - v;   // exclusive within tile
  if (t == 255) tile_sum[b] = s[255];
}

__global__ __launch_bounds__(256) void sum_scan_kernel(
    const int* __restrict__ tile_sum, int* __restrict__ tile_base) {
  __shared__ int s[256];
  int t = threadIdx.x;
  int v = (t < NTILES) ? tile_sum[t] : 0;
  s[t] = v;
  __syncthreads();
#pragma unroll
  for (int off = 1; off < 256; off <<= 1) {
    int x = (t >= off) ? s[t - off] : 0;
    __syncthreads();
    s[t] += x;
    __syncthreads();
  }
  if (t < NTILES) tile_base[t] = s[t] - v;   // exclusive across tiles
}

__global__ __launch_bounds__(256) void scan_write_kernel(
    const int* __restrict__ cnt, const int* __restrict__ tile_pref,
    const int* __restrict__ tile_base, int* __restrict__ row_ptr,
    int* __restrict__ cursor, float* __restrict__ dinv) {
  int b = blockIdx.x, t = threadIdx.x;
  int i = b * 256 + t;
  if (i < NNODES) {
    int base = tile_base[b] + tile_pref[i];
    row_ptr[i] = base;
    cursor[i] = base;
    dinv[i] = rsqrtf((float)(cnt[i] + 1));  // +1 self loop
    if (i == NNODES - 1) row_ptr[NNODES] = base + cnt[i];
  }
}

__global__ void fill_kernel(const int* src, const int* dst, int* cursor, int* col_idx) {
  int i = blockIdx.x * 256 + threadIdx.x;
  if (i < NEDGES) {
    int p = atomicAdd(&cursor[dst[i]], 1);
    col_idx[p] = src[i];
  }
}

// ------- merged prep: x f32->bf16 + all 5 weight transpose/hi-lo splits ----
__global__ __launch_bounds__(256) void prep_all(
    const float* __restrict__ x, ushort_t* __restrict__ xbf,
    const float* __restrict__ W1, ushort_t* __restrict__ W1h, ushort_t* __restrict__ W1l,
    const float* __restrict__ W2, ushort_t* __restrict__ W2h, ushort_t* __restrict__ W2l,
    const float* __restrict__ W3, ushort_t* __restrict__ W3h, ushort_t* __restrict__ W3l,
    const float* __restrict__ W4, ushort_t* __restrict__ W4h, ushort_t* __restrict__ W4l,
    const float* __restrict__ Wl, ushort_t* __restrict__ Wlh, ushort_t* __restrict__ Wll) {
  int b = blockIdx.x;
  if (b < XPREP_BLOCKS) {
    size_t i = ((size_t)b * 256 + threadIdx.x) * 8;
    float4 p0 = *(const float4*)(x + i);
    float4 p1 = *(const float4*)(x + i + 4);
    uint4 u;
    u.x = (unsigned int)f2bf(p0.x) | ((unsigned int)f2bf(p0.y) << 16);
    u.y = (unsigned int)f2bf(p0.z) | ((unsigned int)f2bf(p0.w) << 16);
    u.z = (unsigned int)f2bf(p1.x) | ((unsigned int)f2bf(p1.y) << 16);
    u.w = (unsigned int)f2bf(p1.z) | ((unsigned int)f2bf(p1.w) << 16);
    *(uint4*)(xbf + i) = u;
    return;
  }
  int t = (b - XPREP_BLOCKS) * 256 + threadIdx.x;
  const float* W; ushort_t* hi; ushort_t* lo; int K, N;
  if (t < 49152)       { W = W1; hi = W1h; lo = W1l; K = 384; N = 128; }
  else if (t < 98304)  { W = W2; hi = W2h; lo = W2l; K = 128; N = 384; t -= 49152; }
  else if (t < 196608) { W = W3; hi = W3h; lo = W3l; K = 384; N = 256; t -= 98304; }
  else if (t < 294912) { W = W4; hi = W4h; lo = W4l; K = 256; N = 384; t -= 196608; }
  else                 { W = Wl; hi = Wlh; lo = Wll; K = 384; N = 128; t -= 294912; }
  int n = t / K, k = t - n * K;
  float w = W[(size_t)k * N + n];
  unsigned short h = f2bf(w);
  hi[t] = h;
  lo[t] = f2bf(w - bf2f(h));
}

// ---------------- aggregation (CSR, one wave per node, bf16 act) ----------
// Inputs PRE-SCALED by source dinv. out[i] = act(dinv[i]*sum + bias)[*dinv[i]]
// mode 0: plain; 1: +bias leaky_relu(0.01)

template <int WPL>
__device__ __forceinline__ void load_row(const ushort_t* p, float* f) {
  if (WPL == 2) {
    unsigned int u = *(const unsigned int*)p;
    f[0] = bf2f((unsigned short)(u & 0xffff));
    f[1] = bf2f((unsigned short)(u >> 16));
  } else {
    uint2 u = *(const uint2*)p;
    f[0] = bf2f((unsigned short)(u.x & 0xffff));
    f[1] = bf2f((unsigned short)(u.x >> 16));
    f[2] = bf2f((unsigned short)(u.y & 0xffff));
    f[3] = bf2f((unsigned short)(u.y >> 16));
  }
}

template <int WPL>
__global__ __launch_bounds__(256) void agg_kernel(
    const ushort_t* __restrict__ in, ushort_t* __restrict__ out,
    const int* __restrict__ row_ptr, const int* __restrict__ col_idx,
    const float* __restrict__ dinv, const float* __restrict__ bias,
    int mode, int scale_store) {
  const int W = WPL * 64;
  // wave-uniform by construction; readfirstlane forces SGPR so row_ptr/col_idx
  // index loads become scalar (SMEM) and gathers get saddr-form addressing.
  int wid = __builtin_amdgcn_readfirstlane(blockIdx.x * 4 + (int)(threadIdx.x >> 6));
  int lane = threadIdx.x & 63;
  int co = lane * WPL;
  const ushort_t* base = in + co;
  float acc[WPL];
  {
    float v[WPL];
    load_row<WPL>(base + (size_t)wid * W, v);
#pragma unroll
    for (int c = 0; c < WPL; ++c) acc[c] = v[c];
  }
  int e = row_ptr[wid], e1 = row_ptr[wid + 1];
  for (; e + 16 <= e1; e += 16) {
    int j[16];
#pragma unroll
    for (int q = 0; q < 16; ++q) j[q] = col_idx[e + q];
    float v[16][WPL];
#pragma unroll
    for (int q = 0; q < 16; ++q) load_row<WPL>(base + (size_t)j[q] * W, v[q]);
#pragma unroll
    for (int c = 0; c < WPL; ++c) {
      float s0 = (v[0][c] + v[1][c]) + (v[2][c] + v[3][c]);
      float s1 = (v[4][c] + v[5][c]) + (v[6][c] + v[7][c]);
      float s2 = (v[8][c] + v[9][c]) + (v[10][c] + v[11][c]);
      float s3 = (v[12][c] + v[13][c]) + (v[14][c] + v[15][c]);
      acc[c] += (s0 + s1) + (s2 + s3);
    }
  }
  for (; e + 4 <= e1; e += 4) {
    int j0 = col_idx[e], j1 = col_idx[e + 1], j2 = col_idx[e + 2], j3 = col_idx[e + 3];
    float v0[WPL], v1[WPL], v2[WPL], v3[WPL];
    load_row<WPL>(base + (size_t)j0 * W, v0);
    load_row<WPL>(base + (size_t)j1 * W, v1);
    load_row<WPL>(base + (size_t)j2 * W, v2);
    load_row<WPL>(base + (size_t)j3 * W, v3);
#pragma unroll
    for (int c = 0; c < WPL; ++c) acc[c] += (v0[c] + v1[c]) + (v2[c] + v3[c]);
  }
  for (; e < e1; ++e) {
    int j = col_idx[e];
    float v[WPL];
    load_row<WPL>(base + (size_t)j * W, v);
#pragma unroll
    for (int c = 0; c < WPL; ++c) acc[c] += v[c];
  }
  float di = dinv[wid];
  unsigned short o[WPL];
  if (mode) {
    float bb[WPL];
    if constexpr (WPL == 2) {
      float2 b2 = *(const float2*)(bias + co); bb[0] = b2.x; bb[1] = b2.y;
    } else {
      float4 b4 = *(const float4*)(bias + co);
      bb[0] = b4.x; bb[1] = b4.y; bb[2] = b4.z; bb[3] = b4.w;
    }
    float sc = scale_store ? di : 1.f;
#pragma unroll
    for (int c = 0; c < WPL; ++c) {
      float v = acc[c] * di + bb[c];
      v = v > 0.f ? v : 0.01f * v;
      o[c] = f2bf(v * sc);
    }
  } else {
#pragma unroll
    for (int c = 0; c < WPL; ++c) o[c] = f2bf(acc[c] * di);
  }
  if constexpr (WPL == 2) {
    *(unsigned int*)(out + (size_t)wid * W + co) =
        (unsigned int)o[0] | ((unsigned int)o[1] << 16);
  } else {
    uint2 u;
    u.x = (unsigned int)o[0] | ((unsigned int)o[1] << 16);
    u.y = (unsigned int)o[2] | ((unsigned int)o[3] << 16);
    *(uint2*)(out + (size_t)wid * W + co) = u;
  }
}

// ---------------- MFMA GEMM: C = A[M,K] @ (Bhi+Blo)[N,K]^T ----------------
// TBM x TBN tile, BK=32, 4 waves (2x2), 16x16x32 bf16 MFMA, hi/lo split
// weights (f32-accurate). Staging via global_load_lds (16B).
// mode 0: raw; 1: +bias leaky; 2: +bias relu. scale_store: *dinv[row].

#define BK 32

template <int TBM, int TBN>
__global__ __launch_bounds__(256, TBM == 64 ? 6 : 4) void gemm_mfma(
    const ushort_t* __restrict__ A, const ushort_t* __restrict__ Bhi,
    const ushort_t* __restrict__ Blo, void* __restrict__ Cv,
    const float* __restrict__ bias, const float* __restrict__ dinv,
    int M, int K, int ldc, int mode, int scale_store, int out_f32) {
  constexpr int FR = TBM / 32;        // A fragments per wave
  constexpr int FG = TBN / 32;        // B fragments per wave
  constexpr int AIT = TBM / 64;       // A staging iterations (256 thr, 16B each)
  constexpr int BIT = TBN / 64;       // B staging iterations
  __shared__ ushort_t As[TBM * BK];
  __shared__ ushort_t Bh[TBN * BK];
  __shared__ ushort_t Bl[TBN * BK];
  int tid = threadIdx.x;
  int lane = tid & 63, w = tid >> 6;
  int wm = w & 1, wn = w >> 1;
  int m0 = blockIdx.x * TBM, n0 = blockIdx.y * TBN;
  floatx4 acc[FR][FG] = {};
  int nkt = K / BK;
  for (int kt = 0; kt < nkt; ++kt) {
    int kb = kt * BK;
    __syncthreads();  // previous iteration's LDS reads complete
#pragma unroll
    for (int it = 0; it < AIT; ++it) {
      int s = it * 256 + tid;
      int row = s >> 2, ks = (s & 3) * 8;
      int gr = m0 + row; if (gr > M - 1) gr = M - 1;  // clamp; stores guarded
      gload_lds16(A + (size_t)gr * K + kb + ks,
                  As + (size_t)(it * 256 + w * 64) * 8);
    }
#pragma unroll
    for (int it = 0; it < BIT; ++it) {
      int s = it * 256 + tid;
      int row = s >> 2, ks = (s & 3) * 8;
      gload_lds16(Bhi + (size_t)(n0 + row) * K + kb + ks,
                  Bh + (size_t)(it * 256 + w * 64) * 8);
      gload_lds16(Blo + (size_t)(n0 + row) * K + kb + ks,
                  Bl + (size_t)(it * 256 + w * 64) * 8);
    }
    __syncthreads();  // drains vmcnt (incl. LDS-DMA) and lgkm
    short8 af[FR], fh[FG], fl[FG];
#pragma unroll
    for (int f = 0; f < FR; ++f)
      af[f] = *(const short8*)&As[(wm * (TBM / 2) + f * 16 + (lane & 15)) * BK + (lane >> 4) * 8];
#pragma unroll
    for (int g = 0; g < FG; ++g) {
      int o = (wn * (TBN / 2) + g * 16 + (lane & 15)) * BK + (lane >> 4) * 8;
      fh[g] = *(const short8*)&Bh[o];
      fl[g] = *(const short8*)&Bl[o];
    }
#pragma unroll
    for (int f = 0; f < FR; ++f)
#pragma unroll
      for (int g = 0; g < FG; ++g) {
        acc[f][g] = __builtin_amdgcn_mfma_f32_16x16x32_bf16(af[f], fh[g], acc[f][g], 0, 0, 0);
        acc[f][g] = __builtin_amdgcn_mfma_f32_16x16x32_bf16(af[f], fl[g], acc[f][g], 0, 0, 0);
      }
  }
  int cr = lane >> 4, cc = lane & 15;
#pragma unroll
  for (int f = 0; f < FR; ++f) {
#pragma unroll
    for (int r = 0; r < 4; ++r) {
      int row = m0 + wm * (TBM / 2) + f * 16 + cr * 4 + r;
      if (row >= M) continue;
      float sc = scale_store ? dinv[row] : 1.f;
#pragma unroll
      for (int g = 0; g < FG; ++g) {
        int col = n0 + wn * (TBN / 2) + g * 16 + cc;
        float v = acc[f][g][r];
        if (mode) {
          v += bias[col];
          v = (mode == 1) ? (v > 0.f ? v : 0.01f * v) : (v > 0.f ? v : 0.f);
        }
        v *= sc;
        if (out_f32) ((float*)Cv)[(size_t)row * ldc + col] = v;
        else ((ushort_t*)Cv)[(size_t)row * ldc + col] = f2bf(v);
      }
    }
  }
}

// ---------------- driver ----------------

extern "C" void kernel_launch(void* const* d_in, const int* in_sizes, int n_in,
                              void* d_out, int out_size, void* d_ws, size_t ws_size,
                              hipStream_t stream) {
  const float* x  = (const float*)d_in[0];
  const int* ei   = (const int*)d_in[1];
  const float* W1 = (const float*)d_in[2];
  const float* b1 = (const float*)d_in[3];
  const float* W2 = (const float*)d_in[4];
  const float* b2 = (const float*)d_in[5];
  const float* W3 = (const float*)d_in[6];
  const float* b3 = (const float*)d_in[7];
  const float* W4 = (const float*)d_in[8];
  const float* b4 = (const float*)d_in[9];
  const float* Wl = (const float*)d_in[10];
  const float* bl = (const float*)d_in[11];

  char* p = (char*)d_ws;
  auto alloc = [&](size_t bytes) {
    char* r = p;
    p += (bytes + 255) & ~(size_t)255;
    return r;
  };
  int* cnt       = (int*)alloc((size_t)NNODES * 4);
  int* cursor    = (int*)alloc((size_t)NNODES * 4);
  int* row_ptr   = (int*)alloc((size_t)(NNODES + 1) * 4);
  float* dinv    = (float*)alloc((size_t)NNODES * 4);
  int* col_idx   = (int*)alloc((size_t)NEDGES * 4);
  int* tile_pref = (int*)alloc((size_t)NNODES * 4);
  int* tile_sum  = (int*)alloc(256 * 4);
  int* tile_base = (int*)alloc(256 * 4);
  ushort_t* W1h = (ushort_t*)alloc(49152 * 2); ushort_t* W1l = (ushort_t*)alloc(49152 * 2);
  ushort_t* W2h = (ushort_t*)alloc(49152 * 2); ushort_t* W2l = (ushort_t*)alloc(49152 * 2);
  ushort_t* W3h = (ushort_t*)alloc(98304 * 2); ushort_t* W3l = (ushort_t*)alloc(98304 * 2);
  ushort_t* W4h = (ushort_t*)alloc(98304 * 2); ushort_t* W4l = (ushort_t*)alloc(98304 * 2);
  ushort_t* Wlh = (ushort_t*)alloc(49152 * 2); ushort_t* Wll = (ushort_t*)alloc(49152 * 2);
  ushort_t* actA = (ushort_t*)alloc((size_t)NNODES * 384 * 2);
  ushort_t* actB = (ushort_t*)alloc((size_t)NNODES * 384 * 2);
  // xbf aliases actB: actB is first written by L1-agg, by which time the
  // bf16 copy of x (read only by the L1 gemm) is dead.
  ushort_t* xbf = actB;

  const int* src = ei;
  const int* dst = ei + NEDGES;

  hipMemsetAsync(cnt, 0, (size_t)NNODES * 4, stream);
  hist_kernel<<<(NEDGES + 255) / 256, 256, 0, stream>>>(dst, cnt);
  tile_scan_kernel<<<NTILES, 256, 0, stream>>>(cnt, tile_pref, tile_sum);
  sum_scan_kernel<<<1, 256, 0, stream>>>(tile_sum, tile_base);
  scan_write_kernel<<<NTILES, 256, 0, stream>>>(cnt, tile_pref, tile_base, row_ptr, cursor, dinv);
  fill_kernel<<<(NEDGES + 255) / 256, 256, 0, stream>>>(src, dst, cursor, col_idx);

  prep_all<<<XPREP_BLOCKS + WPREP_BLOCKS, 256, 0, stream>>>(
      x, xbf, W1, W1h, W1l, W2, W2h, W2l, W3, W3h, W3l, W4, W4h, W4l, Wl, Wlh, Wll);

  dim3 blk(256);
  int gm64  = (NNODES + 63) / 64;    // 782
  int gm128 = (NNODES + 127) / 128;  // 391
  int nagg = NNODES / 4;             // 12500 blocks, one wave per node

  // L1 (384->128): gemm reads xbf (pre-scaled store), agg(+b1, leaky, pre-scaled)
  gemm_mfma<64, 64><<<dim3(gm64, 2), blk, 0, stream>>>(xbf, W1h, W1l, actA, (const float*)0, dinv, NNODES, 384, 128, 0, 1, 0);
  agg_kernel<2><<<nagg, blk, 0, stream>>>(actA, actB, row_ptr, col_idx, dinv, b1, 1, 1);
  // L2 (128->384): agg (plain), gemm(+b2, leaky)
  agg_kernel<2><<<nagg, blk, 0, stream>>>(actB, actA, row_ptr, col_idx, dinv, (const float*)0, 0, 0);
  gemm_mfma<128, 128><<<dim3(gm128, 3), blk, 0, stream>>>(actA, W2h, W2l, actB, b2, dinv, NNODES, 128, 384, 1, 0, 0);
  // L3 (384->256): gemm (pre-scaled store), agg(+b3, leaky, pre-scaled store)
  gemm_mfma<128, 128><<<dim3(gm128, 2), blk, 0, stream>>>(actB, W3h, W3l, actA, (const float*)0, dinv, NNODES, 384, 256, 0, 1, 0);
  agg_kernel<4><<<nagg, blk, 0, stream>>>(actA, actB, row_ptr, col_idx, dinv, b3, 1, 1);
  // L4 (256->384): agg (plain), gemm(+b4, leaky)
  agg_kernel<4><<<nagg, blk, 0, stream>>>(actB, actA, row_ptr, col_idx, dinv, (const float*)0, 0, 0);
  gemm_mfma<128, 128><<<dim3(gm128, 3), blk, 0, stream>>>(actA, W4h, W4l, actB, b4, dinv, NNODES, 256, 384, 1, 0, 0);
  // final linear (384->128) + relu -> d_out (f32)
  gemm_mfma<64, 64><<<dim3(gm64, 2), blk, 0, stream>>>(actB, Wlh, Wll, d_out, bl, dinv, NNODES, 384, 128, 2, 0, 1);
}